// Round 3
// baseline (226.400 us; speedup 1.0000x reference)
//
#include <hip/hip_runtime.h>
#include <hip/hip_bf16.h>

#define NEXP 16
#define KDIM 1024
#define ODIM 4096
#define NTOK 2048

#define BM 128
#define BN 64
#define BK 64
#define NCH 2                       // max token-chunks per expert (n_e <= 256)
#define KIT (KDIM / BK)             // 16
#define NBLK (NEXP * (ODIM / BN) * NCH)   // 2048

typedef __attribute__((ext_vector_type(8))) short short8;
typedef __attribute__((ext_vector_type(4))) float f32x4;

__device__ __forceinline__ unsigned short f2bf(float f) {
    __hip_bfloat16 h = __float2bfloat16(f);
    return __builtin_bit_cast(unsigned short, h);
}

__device__ __forceinline__ short8 pack8(float4 a, float4 b) {
    short8 r;
    r[0] = (short)f2bf(a.x); r[1] = (short)f2bf(a.y);
    r[2] = (short)f2bf(a.z); r[3] = (short)f2bf(a.w);
    r[4] = (short)f2bf(b.x); r[5] = (short)f2bf(b.y);
    r[6] = (short)f2bf(b.z); r[7] = (short)f2bf(b.w);
    return r;
}

// ---------------------------------------------------------------------------
// Kernel 1: deterministic counting sort of tokens by expert.
// hist padded to 17 ints/row so per-thread rows spread across banks.
// ---------------------------------------------------------------------------
__global__ __launch_bounds__(256) void moe_sort(const int* __restrict__ gate,
                                                int* __restrict__ perm,
                                                int* __restrict__ offs) {
    __shared__ int lgate[NTOK];
    __shared__ int hist[256][NEXP + 1];
    __shared__ int base[NEXP];
    const int t = threadIdx.x;
    for (int i = t; i < NTOK; i += 256) lgate[i] = gate[i];
    #pragma unroll
    for (int e = 0; e < NEXP; ++e) hist[t][e] = 0;
    __syncthreads();
    const int TPT = NTOK / 256;
    for (int j = 0; j < TPT; ++j) hist[t][lgate[t * TPT + j]]++;
    __syncthreads();
    if (t < NEXP) {
        int s = 0;
        for (int i = 0; i < 256; ++i) { int v = hist[i][t]; hist[i][t] = s; s += v; }
        base[t] = s;
    }
    __syncthreads();
    if (t == 0) {
        int s = 0;
        for (int e = 0; e < NEXP; ++e) { int v = base[e]; base[e] = s; offs[e] = s; s += v; }
        offs[NEXP] = s;
    }
    __syncthreads();
    #pragma unroll
    for (int e = 0; e < NEXP; ++e) hist[t][e] += base[e];
    for (int j = 0; j < TPT; ++j) {
        int tok = t * TPT + j;
        int e = lgate[tok];
        int pos = hist[t][e]++;
        perm[pos] = tok;
    }
}

// ---------------------------------------------------------------------------
// Kernel 2: grouped GEMM.
// Coalesced staging (thread t = k-octet t&7 of row t>>3) + XOR row-swizzle
// LDS layout [oct][row ^ oct] so staging writes hit distinct bank groups
// (R2's un-swizzled writes cost 2.5e7 conflict cycles).
// Depth-2 register prefetch: two named reg sets (Ra/Rb), tile t+2 issued
// before COMPUTE(t); the vmcnt wait in CVTWRITE(t+1) is for loads issued a
// full iteration earlier -> HBM latency spans a whole compute+barrier step.
// ---------------------------------------------------------------------------
#define ASW(b, o, r) As[b][o][(r) ^ (o)]
#define BSW(b, o, r) Bs[b][o][(r) ^ (o)]

__global__ __launch_bounds__(256, 3) void moe_gemm(
    const float* __restrict__ inp,
    const float* __restrict__ weight,
    const int* __restrict__ perm,
    const int* __restrict__ offs,
    float* __restrict__ out)
{
    const int bid = blockIdx.x;
    const int v   = (bid & 7) * (NBLK / 8) + (bid >> 3);   // XCD-contiguous remap
    const int e   = v >> 7;            // 128 blocks per expert
    const int rem = v & 127;
    const int oc  = (rem >> 1) * BN;
    const int ch  = rem & 1;

    const int beg = offs[e], end = offs[e + 1];
    const int chunk0 = beg + ch * BM;
    if (chunk0 >= end) return;
    int rows = end - chunk0; if (rows > BM) rows = BM;

    __shared__ short As[2][8][BM][8];   // 32 KB: [buf][k-octet][row^oct][8 bf16]
    __shared__ short Bs[2][8][BN][8];   // 16 KB

    const int t    = threadIdx.x;
    const int lane = t & 63;
    const int w    = t >> 6;
    const int wm   = w >> 1;            // wave row-half  (0..1)
    const int wn   = w & 1;             // wave col-half  (0..1)

    // ---- staging map: thread t owns k-octet (t&7) of rows {t>>3 (+32k)} ----
    const int oct = t & 7;
    const int rr  = t >> 3;

    const float* aptr[4]; bool avalid[4];
    #pragma unroll
    for (int rep = 0; rep < 4; ++rep) {
        int r = rr + 32 * rep;
        avalid[rep] = (r < rows);
        int tok = avalid[rep] ? perm[chunk0 + r] : 0;
        aptr[rep] = inp + (size_t)tok * KDIM + oct * 8;
    }
    const float* bptr0 = weight + ((size_t)e * ODIM + oc + rr) * KDIM + oct * 8;
    const float* bptr1 = bptr0 + (size_t)32 * KDIM;

    // two staging register sets (depth-2 pipeline) — static names (no
    // runtime-indexed arrays -> stays in VGPRs)
    float4 Ra_a0[4], Ra_a1[4], Ra_b0[2], Ra_b1[2];
    float4 Rb_a0[4], Rb_a1[4], Rb_b0[2], Rb_b1[2];

    f32x4 acc[4][2];
    #pragma unroll
    for (int m = 0; m < 4; ++m)
        #pragma unroll
        for (int n = 0; n < 2; ++n)
            acc[m][n] = (f32x4){0.f, 0.f, 0.f, 0.f};

    const bool wactive = (wm * 64) < rows;
    const int  frow = lane & 15;
    const int  fks  = lane >> 4;

#define LOADG(S, kk) {                                                        \
        _Pragma("unroll")                                                     \
        for (int rep = 0; rep < 4; ++rep) {                                   \
            if (avalid[rep]) {                                                \
                S##_a0[rep] = *(const float4*)(aptr[rep] + (kk));             \
                S##_a1[rep] = *(const float4*)(aptr[rep] + (kk) + 4);         \
            }                                                                 \
        }                                                                     \
        S##_b0[0] = *(const float4*)(bptr0 + (kk));                           \
        S##_b1[0] = *(const float4*)(bptr0 + (kk) + 4);                       \
        S##_b0[1] = *(const float4*)(bptr1 + (kk));                           \
        S##_b1[1] = *(const float4*)(bptr1 + (kk) + 4);                       \
    }

#define CVTWRITE(S, buf) {                                                    \
        _Pragma("unroll")                                                     \
        for (int rep = 0; rep < 4; ++rep)                                     \
            if (avalid[rep])                                                  \
                *(short8*)(&ASW(buf, oct, rr + 32 * rep)[0]) =                \
                    pack8(S##_a0[rep], S##_a1[rep]);                          \
        *(short8*)(&BSW(buf, oct, rr)[0])      = pack8(S##_b0[0], S##_b1[0]); \
        *(short8*)(&BSW(buf, oct, rr + 32)[0]) = pack8(S##_b0[1], S##_b1[1]); \
    }

    auto COMPUTE = [&](int buf) {
        if (!wactive) return;           // wave-uniform skip, no barrier inside
        short8 bf[2][2];
        #pragma unroll
        for (int kk = 0; kk < 2; ++kk)
            #pragma unroll
            for (int n = 0; n < 2; ++n)
                bf[kk][n] = *(const short8*)(&BSW(buf, kk * 4 + fks, wn * 32 + n * 16 + frow)[0]);
        #pragma unroll
        for (int kk = 0; kk < 2; ++kk)
            #pragma unroll
            for (int m = 0; m < 4; ++m) {
                short8 af = *(const short8*)(&ASW(buf, kk * 4 + fks, wm * 64 + m * 16 + frow)[0]);
                #pragma unroll
                for (int n = 0; n < 2; ++n)
                    acc[m][n] = __builtin_amdgcn_mfma_f32_16x16x32_bf16(af, bf[kk][n], acc[m][n], 0, 0, 0);
            }
    };

    // ---- pipeline: tiles 0..15; Ra/Rb alternate; LDS double-buffered ----
    LOADG(Ra, 0);
    LOADG(Rb, BK);
    CVTWRITE(Ra, 0);                    // waits Ra's 12 loads; Rb's stay in flight
    __syncthreads();
    int cur = 0;
    for (int p = 0; p < 7; ++p) {       // pair-unrolled: static reg-set names
        LOADG(Ra, (2 * p + 2) * BK);
        COMPUTE(cur);
        CVTWRITE(Rb, cur ^ 1);
        __syncthreads();
        cur ^= 1;
        LOADG(Rb, (2 * p + 3) * BK);
        COMPUTE(cur);
        CVTWRITE(Ra, cur ^ 1);
        __syncthreads();
        cur ^= 1;
    }
    COMPUTE(cur);                       // tile 14
    CVTWRITE(Rb, cur ^ 1);              // tile 15
    __syncthreads();
    cur ^= 1;
    COMPUTE(cur);                       // tile 15

    // ---- epilogue: C layout col=lane&15, row=(lane>>4)*4+reg ----
    if (wactive) {
        const int col0  = oc + wn * 32 + frow;
        const int rbase = wm * 64 + fks * 4;
        #pragma unroll
        for (int m = 0; m < 4; ++m) {
            #pragma unroll
            for (int reg = 0; reg < 4; ++reg) {
                int r = rbase + m * 16 + reg;
                if (r < rows) {
                    int tok = perm[chunk0 + r];
                    float* orow = out + (size_t)tok * ODIM + col0;
                    #pragma unroll
                    for (int n = 0; n < 2; ++n)
                        orow[n * 16] = acc[m][n][reg];
                }
            }
        }
    }
#undef LOADG
#undef CVTWRITE
}

extern "C" void kernel_launch(void* const* d_in, const int* in_sizes, int n_in,
                              void* d_out, int out_size, void* d_ws, size_t ws_size,
                              hipStream_t stream) {
    const float* inp    = (const float*)d_in[0];
    const int*   gate   = (const int*)d_in[1];
    const float* weight = (const float*)d_in[2];
    float*       out    = (float*)d_out;

    int* perm = (int*)d_ws;
    int* offs = perm + NTOK;

    moe_sort<<<1, 256, 0, stream>>>(gate, perm, offs);
    moe_gemm<<<NBLK, 256, 0, stream>>>(inp, weight, perm, offs, out);
}

// Round 4
// 139.950 us; speedup vs baseline: 1.6177x; 1.6177x over previous
//
#include <hip/hip_runtime.h>
#include <hip/hip_bf16.h>

#define NEXP 16
#define KDIM 1024
#define ODIM 4096
#define NTOK 2048

#define BM   256                    // tokens resident per block (covers n_e)
#define BN   128                    // output cols per block
#define KC   64                     // K-chunk in LDS per phase
#define NPH  (KDIM / KC)            // 16 phases
#define NBLK (NEXP * (ODIM / BN))   // 512 blocks

typedef __attribute__((ext_vector_type(8))) short short8;
typedef __attribute__((ext_vector_type(4))) float f32x4;

__device__ __forceinline__ unsigned short f2bf(float f) {
    __hip_bfloat16 h = __float2bfloat16(f);
    return __builtin_bit_cast(unsigned short, h);
}

__device__ __forceinline__ short8 pack8(float4 a, float4 b) {
    short8 r;
    r[0] = (short)f2bf(a.x); r[1] = (short)f2bf(a.y);
    r[2] = (short)f2bf(a.z); r[3] = (short)f2bf(a.w);
    r[4] = (short)f2bf(b.x); r[5] = (short)f2bf(b.y);
    r[6] = (short)f2bf(b.z); r[7] = (short)f2bf(b.w);
    return r;
}

// ---------------------------------------------------------------------------
// Kernel 1: deterministic counting sort of tokens by expert (unchanged).
// ---------------------------------------------------------------------------
__global__ __launch_bounds__(256) void moe_sort(const int* __restrict__ gate,
                                                int* __restrict__ perm,
                                                int* __restrict__ offs) {
    __shared__ int lgate[NTOK];
    __shared__ int hist[256][NEXP + 1];
    __shared__ int base[NEXP];
    const int t = threadIdx.x;
    for (int i = t; i < NTOK; i += 256) lgate[i] = gate[i];
    #pragma unroll
    for (int e = 0; e < NEXP; ++e) hist[t][e] = 0;
    __syncthreads();
    const int TPT = NTOK / 256;
    for (int j = 0; j < TPT; ++j) hist[t][lgate[t * TPT + j]]++;
    __syncthreads();
    if (t < NEXP) {
        int s = 0;
        for (int i = 0; i < 256; ++i) { int v = hist[i][t]; hist[i][t] = s; s += v; }
        base[t] = s;
    }
    __syncthreads();
    if (t == 0) {
        int s = 0;
        for (int e = 0; e < NEXP; ++e) { int v = base[e]; base[e] = s; offs[e] = s; s += v; }
        offs[NEXP] = s;
    }
    __syncthreads();
    #pragma unroll
    for (int e = 0; e < NEXP; ++e) hist[t][e] += base[e];
    for (int j = 0; j < TPT; ++j) {
        int tok = t * TPT + j;
        int e = lgate[tok];
        int pos = hist[t][e]++;
        perm[pos] = tok;
    }
}

// ---------------------------------------------------------------------------
// Kernel 2: A-resident grouped GEMM.
// Block = (expert, 128 out-cols). All <=256 expert tokens' A rows stay in LDS
// (bf16) per 64-wide K-chunk, double-buffered (64 KB). Weight W streams
// DIRECT to registers (each lane loads its own MFMA B-fragment; W has zero
// reuse so LDS staging of it is pure overhead) and is read exactly once.
// No barrier inside the W-stream; phase barriers are lgkmcnt-only raw
// barriers so next-phase B loads stay in flight across them (T4).
// A LDS layout: row-major [256][64] bf16 (128B rows) with k-octet XOR
// swizzle (ko ^ (row&7)): writes cover a full permuted 128B line per 8-lane
// cluster; reads are the m201-verified swizzled pattern.
// ---------------------------------------------------------------------------
__global__ __launch_bounds__(512, 1) void moe_gemm(
    const float* __restrict__ inp,
    const float* __restrict__ weight,
    const int* __restrict__ perm,
    const int* __restrict__ offs,
    float* __restrict__ out)
{
    const int bid = blockIdx.x;
    const int v   = (bid & 7) * (NBLK / 8) + (bid >> 3); // 64 consec per XCD = 2 experts
    const int e   = v >> 5;                              // 32 oc-tiles per expert
    const int oc  = (v & 31) * BN;

    const int beg = offs[e], end = offs[e + 1];
    const int nrows_all = end - beg;
    if (nrows_all <= 0) return;

    __shared__ short As[2][BM][KC];    // 64 KB

    const int t    = threadIdx.x;      // 0..511
    const int lane = t & 63;
    const int w    = t >> 6;           // 0..7
    const int wm   = w >> 2;           // row half (128 rows)
    const int wn   = w & 3;            // col group (32 cols)
    const int frow = lane & 15;
    const int fks  = lane >> 4;        // 0..3

    // staging map: thread t = k-octet (t&7) of rows {t>>3 (+64i)}
    const int sko = t & 7;
    const int srb = t >> 3;            // 0..63

    // B fragment base pointers (direct global -> MFMA B operand)
    const float* bp0 = weight + ((size_t)e * ODIM + oc + wn * 32 + frow) * KDIM;
    const float* bp1 = bp0 + (size_t)16 * KDIM;
    const int bko = fks * 8;

#define BARRIER() do {                                            \
        __builtin_amdgcn_sched_barrier(0);                        \
        asm volatile("s_waitcnt lgkmcnt(0)" ::: "memory");        \
        __builtin_amdgcn_s_barrier();                             \
        __builtin_amdgcn_sched_barrier(0);                        \
    } while (0)

    for (int base = 0; base < nrows_all; base += BM) {
        const int rows = (nrows_all - base < BM) ? (nrows_all - base) : BM;
        const int c0   = beg + base;

        // tokens for this thread's 4 staged rows (clamped, unconditional)
        int rc0 = srb;            if (rc0 > rows - 1) rc0 = rows - 1;
        int rc1 = srb + 64;       if (rc1 > rows - 1) rc1 = rows - 1;
        int rc2 = srb + 128;      if (rc2 > rows - 1) rc2 = rows - 1;
        int rc3 = srb + 192;      if (rc3 > rows - 1) rc3 = rows - 1;
        const float* ap0 = inp + (size_t)perm[c0 + rc0] * KDIM + sko * 8;
        const float* ap1 = inp + (size_t)perm[c0 + rc1] * KDIM + sko * 8;
        const float* ap2 = inp + (size_t)perm[c0 + rc2] * KDIM + sko * 8;
        const float* ap3 = inp + (size_t)perm[c0 + rc3] * KDIM + sko * 8;

        f32x4 acc[8][2];
        #pragma unroll
        for (int m = 0; m < 8; ++m) {
            acc[m][0] = (f32x4){0.f, 0.f, 0.f, 0.f};
            acc[m][1] = (f32x4){0.f, 0.f, 0.f, 0.f};
        }

        float4 av0, av1, av2, av3, av4, av5, av6, av7;
        float4 b00a, b00b, b01a, b01b, b10a, b10b, b11a, b11b;

#define ISSUE_A(kc) {                                             \
        av0 = *(const float4*)(ap0 + (kc));                       \
        av1 = *(const float4*)(ap0 + (kc) + 4);                   \
        av2 = *(const float4*)(ap1 + (kc));                       \
        av3 = *(const float4*)(ap1 + (kc) + 4);                   \
        av4 = *(const float4*)(ap2 + (kc));                       \
        av5 = *(const float4*)(ap2 + (kc) + 4);                   \
        av6 = *(const float4*)(ap3 + (kc));                       \
        av7 = *(const float4*)(ap3 + (kc) + 4);                   \
    }

#define CVTWRITE_A(buf) {                                                      \
        int r0 = srb;       *(short8*)&As[buf][r0][(sko ^ (r0 & 7)) * 8] = pack8(av0, av1); \
        int r1 = srb + 64;  *(short8*)&As[buf][r1][(sko ^ (r1 & 7)) * 8] = pack8(av2, av3); \
        int r2 = srb + 128; *(short8*)&As[buf][r2][(sko ^ (r2 & 7)) * 8] = pack8(av4, av5); \
        int r3 = srb + 192; *(short8*)&As[buf][r3][(sko ^ (r3 & 7)) * 8] = pack8(av6, av7); \
    }

#define ISSUE_B(kc) {                                             \
        b00a = *(const float4*)(bp0 + (kc) + bko);                \
        b00b = *(const float4*)(bp0 + (kc) + bko + 4);            \
        b01a = *(const float4*)(bp1 + (kc) + bko);                \
        b01b = *(const float4*)(bp1 + (kc) + bko + 4);            \
        b10a = *(const float4*)(bp0 + (kc) + 32 + bko);           \
        b10b = *(const float4*)(bp0 + (kc) + 32 + bko + 4);      \
        b11a = *(const float4*)(bp1 + (kc) + 32 + bko);           \
        b11b = *(const float4*)(bp1 + (kc) + 32 + bko + 4);      \
    }

#define STEP(pb, s, Ba0, Ba1, Bb0, Bb1) {                                      \
        short8 bf0 = pack8(Ba0, Ba1);                                          \
        short8 bf1 = pack8(Bb0, Bb1);                                          \
        const int ko_r = (s) * 4 + fks;                                        \
        _Pragma("unroll")                                                      \
        for (int m = 0; m < 8; ++m) {                                          \
            int row = wm * 128 + m * 16 + frow;                                \
            short8 af = *(const short8*)&As[pb][row][(ko_r ^ (row & 7)) * 8];  \
            acc[m][0] = __builtin_amdgcn_mfma_f32_16x16x32_bf16(af, bf0, acc[m][0], 0, 0, 0); \
            acc[m][1] = __builtin_amdgcn_mfma_f32_16x16x32_bf16(af, bf1, acc[m][1], 0, 0, 0); \
        }                                                                      \
    }

        // ---- prologue ----
        ISSUE_A(0);
        CVTWRITE_A(0);                 // compiler inserts the vmcnt wait
        BARRIER();
        ISSUE_B(0);

        // ---- 16 phases; B(p+1) issued pre-barrier, survives lgkm-only bar ----
        for (int p = 0; p < NPH; ++p) {
            const int pb = p & 1;
            const int kn = (p + 1 < NPH ? p + 1 : NPH - 1) * KC;
            ISSUE_A(kn);
            STEP(pb, 0, b00a, b00b, b01a, b01b);
            STEP(pb, 1, b10a, b10b, b11a, b11b);
            ISSUE_B(kn);
            __builtin_amdgcn_sched_barrier(0);
            CVTWRITE_A(pb ^ 1);        // waits A loads (B stays in flight)
            BARRIER();
        }

        // ---- epilogue: C layout col=lane&15, row=(lane>>4)*4+reg ----
        const int col0 = oc + wn * 32 + frow;
        #pragma unroll
        for (int m = 0; m < 8; ++m) {
            #pragma unroll
            for (int reg = 0; reg < 4; ++reg) {
                int r = wm * 128 + m * 16 + fks * 4 + reg;
                if (r < rows) {
                    int tok = perm[c0 + r];
                    float* orow = out + (size_t)tok * ODIM + col0;
                    orow[0]  = acc[m][0][reg];
                    orow[16] = acc[m][1][reg];
                }
            }
        }
#undef ISSUE_A
#undef CVTWRITE_A
#undef ISSUE_B
#undef STEP
    }
#undef BARRIER
}

extern "C" void kernel_launch(void* const* d_in, const int* in_sizes, int n_in,
                              void* d_out, int out_size, void* d_ws, size_t ws_size,
                              hipStream_t stream) {
    const float* inp    = (const float*)d_in[0];
    const int*   gate   = (const int*)d_in[1];
    const float* weight = (const float*)d_in[2];
    float*       out    = (float*)d_out;

    int* perm = (int*)d_ws;
    int* offs = perm + NTOK;

    moe_sort<<<1, 256, 0, stream>>>(gate, perm, offs);
    moe_gemm<<<NBLK, 512, 0, stream>>>(inp, weight, perm, offs, out);
}

// Round 5
// 113.241 us; speedup vs baseline: 1.9993x; 1.2359x over previous
//
#include <hip/hip_runtime.h>
#include <hip/hip_bf16.h>

#define NEXP 16
#define KDIM 1024
#define ODIM 4096
#define NTOK 2048

#define BM   256                    // token rows resident per block
#define BN   256                    // output cols per block (8 waves x 32)
#define KC   64                     // K-chunk in LDS per phase
#define NPH  (KDIM / KC)            // 16 phases
#define NBLK (NEXP * (ODIM / BN))   // 256 blocks = 1 per CU

typedef __attribute__((ext_vector_type(8))) short short8;
typedef __attribute__((ext_vector_type(4))) float f32x4;
typedef __attribute__((ext_vector_type(4))) unsigned short u16x4;

__device__ __forceinline__ unsigned short f2bf(float f) {
    __hip_bfloat16 h = __float2bfloat16(f);
    return __builtin_bit_cast(unsigned short, h);
}

__device__ __forceinline__ short8 pack8(float4 a, float4 b) {
    short8 r;
    r[0] = (short)f2bf(a.x); r[1] = (short)f2bf(a.y);
    r[2] = (short)f2bf(a.z); r[3] = (short)f2bf(a.w);
    r[4] = (short)f2bf(b.x); r[5] = (short)f2bf(b.y);
    r[6] = (short)f2bf(b.z); r[7] = (short)f2bf(b.w);
    return r;
}

// ---------------------------------------------------------------------------
// Kernel 1: deterministic counting sort of tokens by expert (unchanged).
// ---------------------------------------------------------------------------
__global__ __launch_bounds__(256) void moe_sort(const int* __restrict__ gate,
                                                int* __restrict__ perm,
                                                int* __restrict__ offs) {
    __shared__ int lgate[NTOK];
    __shared__ int hist[256][NEXP + 1];
    __shared__ int base[NEXP];
    const int t = threadIdx.x;
    for (int i = t; i < NTOK; i += 256) lgate[i] = gate[i];
    #pragma unroll
    for (int e = 0; e < NEXP; ++e) hist[t][e] = 0;
    __syncthreads();
    const int TPT = NTOK / 256;
    for (int j = 0; j < TPT; ++j) hist[t][lgate[t * TPT + j]]++;
    __syncthreads();
    if (t < NEXP) {
        int s = 0;
        for (int i = 0; i < 256; ++i) { int v = hist[i][t]; hist[i][t] = s; s += v; }
        base[t] = s;
    }
    __syncthreads();
    if (t == 0) {
        int s = 0;
        for (int e = 0; e < NEXP; ++e) { int v = base[e]; base[e] = s; offs[e] = s; s += v; }
        offs[NEXP] = s;
    }
    __syncthreads();
    #pragma unroll
    for (int e = 0; e < NEXP; ++e) hist[t][e] += base[e];
    for (int j = 0; j < TPT; ++j) {
        int tok = t * TPT + j;
        int e = lgate[tok];
        int pos = hist[t][e]++;
        perm[pos] = tok;
    }
}

// ---------------------------------------------------------------------------
// Kernel 1.5: gather+convert A to bf16 in perm order. A2[pos][k] bf16.
// One token row per block; thread = one float4 -> ushort4.
// ---------------------------------------------------------------------------
__global__ __launch_bounds__(256) void moe_cvt(const float* __restrict__ inp,
                                               const int* __restrict__ perm,
                                               unsigned short* __restrict__ A2) {
    const int pos = blockIdx.x;
    const int tok = perm[pos];
    const float4* src = (const float4*)(inp + (size_t)tok * KDIM);
    u16x4* dst = (u16x4*)(A2 + (size_t)pos * KDIM);
    float4 v = src[threadIdx.x];
    u16x4 o;
    o[0] = f2bf(v.x); o[1] = f2bf(v.y); o[2] = f2bf(v.z); o[3] = f2bf(v.w);
    dst[threadIdx.x] = o;
}

// ---------------------------------------------------------------------------
// Kernel 2: A-resident grouped GEMM, zero W duplication.
// Block = (expert, 256 out-cols); 8 waves = 8 col-groups of 32 (NO row-split
// -> each W byte loaded exactly once chip-wide, direct to registers).
// All BM=256 token rows in LDS bf16 per K-chunk, double-buffered (64 KB).
// Phase barriers are lgkmcnt-only so in-flight next-phase W loads survive.
// A LDS: [row][64] bf16, k-octet XOR swizzle (ko ^ (row&7)) — write pattern
// 2-lanes/bank (free), read pattern measured 0 conflicts in R4.
// ---------------------------------------------------------------------------
template <bool PRE>
__global__ __launch_bounds__(512, 1) void moe_gemm(
    const float* __restrict__ inp,
    const unsigned short* __restrict__ A2,
    const float* __restrict__ weight,
    const int* __restrict__ perm,
    const int* __restrict__ offs,
    float* __restrict__ out)
{
    const int bid = blockIdx.x;
    const int v   = (bid & 7) * (NBLK / 8) + (bid >> 3); // 32 consec per XCD = 2 experts
    const int e   = v >> 4;                              // 16 oc-tiles per expert
    const int oc  = (v & 15) * BN;

    const int beg = offs[e], end = offs[e + 1];
    const int nall = end - beg;
    if (nall <= 0) return;

    __shared__ short As[2][BM][KC];    // 64 KB

    const int t    = threadIdx.x;      // 0..511
    const int lane = t & 63;
    const int wn   = t >> 6;           // 0..7 col-group
    const int frow = lane & 15;
    const int fks  = lane >> 4;        // 0..3

    // staging map: thread t = k-octet (t&7) of rows {t>>3 (+64i)}
    const int sko = t & 7;
    const int srb = t >> 3;            // 0..63

    // B fragment base pointers (direct global -> MFMA B operand, fp32)
    const float* bp0 = weight + ((size_t)e * ODIM + oc + wn * 32 + frow) * KDIM;
    const float* bp1 = bp0 + (size_t)16 * KDIM;
    const int bko = fks * 8;

#define BARRIER() do {                                            \
        __builtin_amdgcn_sched_barrier(0);                        \
        asm volatile("s_waitcnt lgkmcnt(0)" ::: "memory");        \
        __builtin_amdgcn_s_barrier();                             \
        __builtin_amdgcn_sched_barrier(0);                        \
    } while (0)

    for (int base = 0; base < nall; base += BM) {
        const int rows = (nall - base < BM) ? (nall - base) : BM;
        const int c0   = beg + base;
        const int mfrags = (rows + 15) >> 4;   // active 16-row fragments

        // clamped source rows (unconditional loads; LDS dest rows unclamped)
        const unsigned short* ap2[4];
        const float*          apf[4];
        #pragma unroll
        for (int i = 0; i < 4; ++i) {
            int r = srb + 64 * i; if (r > rows - 1) r = rows - 1;
            if (PRE) ap2[i] = A2 + (size_t)(c0 + r) * KDIM + sko * 8;
            else     apf[i] = inp + (size_t)perm[c0 + r] * KDIM + sko * 8;
        }

        f32x4 acc[16][2];
        #pragma unroll
        for (int m = 0; m < 16; ++m) {
            acc[m][0] = (f32x4){0.f, 0.f, 0.f, 0.f};
            acc[m][1] = (f32x4){0.f, 0.f, 0.f, 0.f};
        }

        short8 sv0, sv1, sv2, sv3;                 // PRE path staging regs
        float4 fa0, fb0, fa1, fb1, fa2, fb2, fa3, fb3;  // !PRE path
        float4 b00a, b00b, b01a, b01b, b10a, b10b, b11a, b11b;

#define ISSUE_A(kc) {                                                    \
        if (PRE) {                                                       \
            sv0 = *(const short8*)(ap2[0] + (kc));                       \
            sv1 = *(const short8*)(ap2[1] + (kc));                       \
            sv2 = *(const short8*)(ap2[2] + (kc));                       \
            sv3 = *(const short8*)(ap2[3] + (kc));                       \
        } else {                                                         \
            fa0 = *(const float4*)(apf[0] + (kc));                       \
            fb0 = *(const float4*)(apf[0] + (kc) + 4);                   \
            fa1 = *(const float4*)(apf[1] + (kc));                       \
            fb1 = *(const float4*)(apf[1] + (kc) + 4);                   \
            fa2 = *(const float4*)(apf[2] + (kc));                       \
            fb2 = *(const float4*)(apf[2] + (kc) + 4);                   \
            fa3 = *(const float4*)(apf[3] + (kc));                       \
            fb3 = *(const float4*)(apf[3] + (kc) + 4);                   \
        }                                                                \
    }

#define CVTWRITE_A(buf) {                                                          \
        int r0 = srb;                                                              \
        int r1 = srb + 64;                                                         \
        int r2 = srb + 128;                                                        \
        int r3 = srb + 192;                                                        \
        *(short8*)&As[buf][r0][(sko ^ (r0 & 7)) * 8] = PRE ? sv0 : pack8(fa0, fb0);\
        *(short8*)&As[buf][r1][(sko ^ (r1 & 7)) * 8] = PRE ? sv1 : pack8(fa1, fb1);\
        *(short8*)&As[buf][r2][(sko ^ (r2 & 7)) * 8] = PRE ? sv2 : pack8(fa2, fb2);\
        *(short8*)&As[buf][r3][(sko ^ (r3 & 7)) * 8] = PRE ? sv3 : pack8(fa3, fb3);\
    }

#define ISSUE_B(kc) {                                             \
        b00a = *(const float4*)(bp0 + (kc) + bko);                \
        b00b = *(const float4*)(bp0 + (kc) + bko + 4);            \
        b01a = *(const float4*)(bp1 + (kc) + bko);                \
        b01b = *(const float4*)(bp1 + (kc) + bko + 4);            \
        b10a = *(const float4*)(bp0 + (kc) + 32 + bko);           \
        b10b = *(const float4*)(bp0 + (kc) + 32 + bko + 4);       \
        b11a = *(const float4*)(bp1 + (kc) + 32 + bko);           \
        b11b = *(const float4*)(bp1 + (kc) + 32 + bko + 4);       \
    }

#define STEP(pb, s, Ba, Bb, Bc, Bd) {                                          \
        short8 bf0 = pack8(Ba, Bb);                                            \
        short8 bf1 = pack8(Bc, Bd);                                            \
        const int ko_r = (s) * 4 + fks;                                        \
        _Pragma("unroll")                                                      \
        for (int m = 0; m < 16; ++m) {                                         \
            if (m < mfrags) {                                                  \
                int row = m * 16 + frow;                                       \
                short8 af = *(const short8*)&As[pb][row][(ko_r ^ (row & 7)) * 8]; \
                acc[m][0] = __builtin_amdgcn_mfma_f32_16x16x32_bf16(af, bf0, acc[m][0], 0, 0, 0); \
                acc[m][1] = __builtin_amdgcn_mfma_f32_16x16x32_bf16(af, bf1, acc[m][1], 0, 0, 0); \
            }                                                                  \
        }                                                                      \
    }

        // ---- prologue ----
        ISSUE_A(0);
        CVTWRITE_A(0);                 // compiler inserts the vmcnt wait
        BARRIER();
        ISSUE_B(0);

        // ---- phases 0..14 with prefetch; B(p+1) survives lgkm-only barrier ----
        for (int p = 0; p < NPH - 1; ++p) {
            const int pb = p & 1;
            const int kn = (p + 1) * KC;
            ISSUE_A(kn);
            STEP(pb, 0, b00a, b00b, b01a, b01b);
            STEP(pb, 1, b10a, b10b, b11a, b11b);
            ISSUE_B(kn);
            __builtin_amdgcn_sched_barrier(0);
            CVTWRITE_A(pb ^ 1);        // waits A loads; B stays in flight
            BARRIER();
        }
        // ---- final phase (no prefetch, no junk loads) ----
        STEP(1, 0, b00a, b00b, b01a, b01b);
        STEP(1, 1, b10a, b10b, b11a, b11b);

        // ---- epilogue: C layout col=lane&15, row=(lane>>4)*4+reg ----
        const int col0 = oc + wn * 32 + frow;
        #pragma unroll
        for (int m = 0; m < 16; ++m) {
            #pragma unroll
            for (int reg = 0; reg < 4; ++reg) {
                int r = m * 16 + fks * 4 + reg;
                if (r < rows) {
                    int tok = perm[c0 + r];
                    float* orow = out + (size_t)tok * ODIM + col0;
                    orow[0]  = acc[m][0][reg];
                    orow[16] = acc[m][1][reg];
                }
            }
        }
#undef ISSUE_A
#undef CVTWRITE_A
#undef ISSUE_B
#undef STEP
    }
#undef BARRIER
}

extern "C" void kernel_launch(void* const* d_in, const int* in_sizes, int n_in,
                              void* d_out, int out_size, void* d_ws, size_t ws_size,
                              hipStream_t stream) {
    const float* inp    = (const float*)d_in[0];
    const int*   gate   = (const int*)d_in[1];
    const float* weight = (const float*)d_in[2];
    float*       out    = (float*)d_out;

    int* perm = (int*)d_ws;                          // 2048 ints
    int* offs = perm + NTOK;                         // 17 ints
    unsigned short* A2 = (unsigned short*)((char*)d_ws + 16384);
    const size_t need = 16384 + (size_t)NTOK * KDIM * 2;   // ~4.2 MB
    const bool pre = (ws_size >= need);              // host-side, deterministic

    moe_sort<<<1, 256, 0, stream>>>(gate, perm, offs);
    if (pre) {
        moe_cvt<<<NTOK, 256, 0, stream>>>(inp, perm, A2);
        moe_gemm<true><<<NBLK, 512, 0, stream>>>(inp, A2, weight, perm, offs, out);
    } else {
        moe_gemm<false><<<NBLK, 512, 0, stream>>>(inp, A2, weight, perm, offs, out);
    }
}